// Round 7
// baseline (15082.399 us; speedup 1.0000x reference)
//
#include <hip/hip_runtime.h>
#include <math.h>

#define NBLK 192
#define BLK  256
#define NSTATE 3072
#define HID  768
typedef unsigned long long u64;
typedef unsigned int u32;

__device__ const float d_AT[7][6] = {
  {0.f,0.f,0.f,0.f,0.f,0.f},
  {0.161f,0.f,0.f,0.f,0.f,0.f},
  {-0.008480655492356989f,0.335480655492357f,0.f,0.f,0.f,0.f},
  {2.8971530571054935f,-6.359448489975075f,4.3622954328695815f,0.f,0.f,0.f},
  {5.325864828439257f,-11.748883564062828f,7.4955393428898365f,-0.09249506636175525f,0.f,0.f},
  {5.86145544294642f,-12.92096931784711f,8.159367898576159f,-0.071584973281401f,-0.028269050394068383f,0.f},
  {0.09646076681806523f,0.01f,0.4798896504144996f,1.379008574103742f,-3.290069515436081f,2.324710524099774f},
};
__device__ const float d_EC[7] = {
  -0.001780011052226f,-0.000816434459657f,0.007880878010262f,-0.144711007173263f,
   0.582357165452555f,-0.458082105929187f,0.015151515151515152f };

// All cross-block state: {tag:hi32, value:lo32} words, ping-pong buffered.
struct GT { u64 h[2][HID]; u64 z[2][NSTATE]; u64 p[2][NBLK]; };
__device__ GT gt;
__device__ int g_abort;

__global__ void reset_kernel(){
  u64* w = reinterpret_cast<u64*>(&gt);
  const int n = (int)(sizeof(GT)/8);
  for (int i = blockIdx.x*blockDim.x + threadIdx.x; i < n; i += gridDim.x*blockDim.x)
    __hip_atomic_store(w + i, 0ull, __ATOMIC_RELAXED, __HIP_MEMORY_SCOPE_AGENT);
  if (blockIdx.x == 0 && threadIdx.x == 0)
    __hip_atomic_store(&g_abort, 0, __ATOMIC_RELAXED, __HIP_MEMORY_SCOPE_AGENT);
}

__device__ __forceinline__ int abort_now(){
  return __hip_atomic_load(&g_abort, __ATOMIC_RELAXED, __HIP_MEMORY_SCOPE_AGENT);
}
__device__ __forceinline__ void raise_abort(){
  __hip_atomic_store(&g_abort, 1, __ATOMIC_RELAXED, __HIP_MEMORY_SCOPE_AGENT);
}
// Busy backoff: ~100 cycles of dependent VALU work. Keeps VALUBusy high so the
// DVFS governor doesn't downclock the chip while we wait on the fabric.
__device__ __forceinline__ void spin_delay(){
  float r = 1.0f + (float)(threadIdx.x & 7);
  #pragma unroll
  for (int i = 0; i < 24; ++i) r = fmaf(r, 1.000001f, 1.0e-7f);
  asm volatile("" :: "v"(r));
}
__device__ __forceinline__ void stT(u64* p, u32 tag, float v){
  u32 b; __builtin_memcpy(&b, &v, 4);
  __hip_atomic_store(p, ((u64)tag << 32) | (u64)b, __ATOMIC_RELAXED, __HIP_MEMORY_SCOPE_AGENT);
}
// Single tagged-word poll; guard bail raises abort (visible fail, never wedge).
__device__ __forceinline__ float pollT1(const u64* p, u32 tag){
  u64* q = const_cast<u64*>(p);
  u64 w = __hip_atomic_load(q, __ATOMIC_RELAXED, __HIP_MEMORY_SCOPE_AGENT);
  u32 guard = 0;
  while ((u32)(w >> 32) != tag){
    if ((guard & 127u) == 127u && abort_now()) break;
    if (++guard > (1u<<18)){ raise_abort(); break; }
    spin_delay();
    w = __hip_atomic_load(q, __ATOMIC_RELAXED, __HIP_MEMORY_SCOPE_AGENT);
  }
  u32 b = (u32)w; float v; __builtin_memcpy(&v, &b, 4); return v;
}
// Batched poll: N words/thread (stride BLK); pipelined first loads; re-poll stale only.
template<int N>
__device__ __forceinline__ void pollN(const u64* src, u32 tag, float* dst){
  const int tid = threadIdx.x;
  u64* s = const_cast<u64*>(src);
  u64 w[N];
  #pragma unroll
  for (int r = 0; r < N; ++r)
    w[r] = __hip_atomic_load(s + tid + BLK*r, __ATOMIC_RELAXED, __HIP_MEMORY_SCOPE_AGENT);
  u32 guard = 0;
  for (;;){
    bool all = true;
    #pragma unroll
    for (int r = 0; r < N; ++r) if ((u32)(w[r] >> 32) != tag) all = false;
    if (all) break;
    if ((guard & 63u) == 63u && abort_now()) break;
    if (++guard > (1u<<17)){ raise_abort(); break; }
    spin_delay();
    #pragma unroll
    for (int r = 0; r < N; ++r)
      if ((u32)(w[r] >> 32) != tag)
        w[r] = __hip_atomic_load(s + tid + BLK*r, __ATOMIC_RELAXED, __HIP_MEMORY_SCOPE_AGENT);
  }
  #pragma unroll
  for (int r = 0; r < N; ++r){
    u32 b = (u32)w[r]; float v; __builtin_memcpy(&v, &b, 4);
    dst[tid + BLK*r] = v;
  }
}

__device__ __forceinline__ float softplus_f(float x){
  return fmaxf(x, 0.0f) + log1pf(expf(-fabsf(x)));
}

__global__ __launch_bounds__(BLK)
void ode_kernel(const float* __restrict__ y0p,
                const float* __restrict__ Win,  const float* __restrict__ bin,
                const float* __restrict__ Whid, const float* __restrict__ bhid,
                const float* __restrict__ Wout, const float* __restrict__ bout,
                const float* __restrict__ eps,  float* __restrict__ out)
{
  __shared__ float zsh[NSTATE];
  __shared__ float hsh[HID];
  __shared__ float kc[7][16];
  __shared__ float ysl[16], y1sl[16];
  __shared__ float red[4];
  __shared__ int s_ab;

  const int tid  = threadIdx.x, blk = blockIdx.x;
  const int wave = tid >> 6, lane = tid & 63;
  const int l16  = lane & 15;
  const int ro   = tid >> 4;                       // local out-slot 0..15
  const int row1 = blk*4 + wave;                   // layer1/hidden row (1 wave/row)
  // Permuted W_out ownership: slot ro=(c,q) -> global out-row c*768 + blk*4 + q.
  // Makes this block's y-slice contain exactly mean[4b..4b+4) and std[4b..4b+4)
  // so output emission is fully block-local (no y exchange phases at all).
  const int orow = (ro >> 2)*HID + blk*4 + (ro & 3);

  const float4* w1  = reinterpret_cast<const float4*>(Win  + (size_t)row1*NSTATE) + lane;
  const float4* wh0 = reinterpret_cast<const float4*>(Whid + ((size_t)0*HID + row1)*HID) + lane;
  const float4* wh1 = reinterpret_cast<const float4*>(Whid + ((size_t)1*HID + row1)*HID) + lane;
  const float4* wh2 = reinterpret_cast<const float4*>(Whid + ((size_t)2*HID + row1)*HID) + lane;
  const float4* wo  = reinterpret_cast<const float4*>(Wout + (size_t)orow*HID) + l16;
  const float b1 = bin[row1];
  const float bh0 = bhid[row1], bh1 = bhid[HID+row1], bh2 = bhid[2*HID+row1];
  const float bo = bout[orow];

  // owned y/z global index for slot tid (tid<16)
  const int gi = (tid >> 2)*HID + blk*4 + (tid & 3);

  if (tid < 16) ysl[tid] = y0p[gi];
  if (tid < 4){ const int e = blk*4 + tid; out[e] = y0p[e] + eps[e]*y0p[HID+e]; }
  __syncthreads();

  u32 hseq = 0, zseq = 0, pseq = 0;
  int kpar = 0;
  auto kslot = [&](int j){ return (j==1) ? (kpar?6:0) : (j==7) ? (kpar?0:6) : (j-1); };

  auto feval = [&](int st, float dte){
    // ---- acquire z ----
    if (st == 0){
      const float4* s4 = reinterpret_cast<const float4*>(y0p);
      float4* d4 = reinterpret_cast<float4*>(zsh);
      #pragma unroll
      for (int r = 0; r < 3; ++r) d4[tid + BLK*r] = s4[tid + BLK*r];
    } else {
      pollN<12>(gt.z[zseq&1], zseq, zsh);
    }
    __syncthreads();
    // ---- layer 1: 768x3072, 1 wave/row ----
    {
      const float4* zl = reinterpret_cast<const float4*>(zsh) + lane;
      float acc = 0.f;
      #pragma unroll
      for (int i = 0; i < 12; ++i){
        float4 w = w1[64*i], x = zl[64*i];
        acc = fmaf(w.x,x.x, fmaf(w.y,x.y, fmaf(w.z,x.z, fmaf(w.w,x.w, acc))));
      }
      acc += __shfl_xor(acc,32); acc += __shfl_xor(acc,16); acc += __shfl_xor(acc,8);
      acc += __shfl_xor(acc,4);  acc += __shfl_xor(acc,2);  acc += __shfl_xor(acc,1);
      ++hseq;
      if (lane == 0) stT(&gt.h[hseq&1][row1], hseq, softplus_f(acc + b1));
    }
    // ---- 3 hidden layers: 768x768 ----
    #pragma unroll
    for (int l = 0; l < 3; ++l){
      pollN<3>(gt.h[hseq&1], hseq, hsh);
      __syncthreads();
      const float4* wr = (l==0) ? wh0 : (l==1) ? wh1 : wh2;
      const float bh  = (l==0) ? bh0 : (l==1) ? bh1 : bh2;
      const float4* hx = reinterpret_cast<const float4*>(hsh) + lane;
      float acc = 0.f;
      #pragma unroll
      for (int i = 0; i < 3; ++i){
        float4 w = wr[64*i], x = hx[64*i];
        acc = fmaf(w.x,x.x, fmaf(w.y,x.y, fmaf(w.z,x.z, fmaf(w.w,x.w, acc))));
      }
      acc += __shfl_xor(acc,32); acc += __shfl_xor(acc,16); acc += __shfl_xor(acc,8);
      acc += __shfl_xor(acc,4);  acc += __shfl_xor(acc,2);  acc += __shfl_xor(acc,1);
      ++hseq;
      if (lane == 0) stT(&gt.h[hseq&1][row1], hseq, softplus_f(acc + bh));
      __syncthreads();            // hsh stable until all lanes finished reading
    }
    // ---- out layer: 3072x768, 16 lanes/row, permuted ownership ----
    pollN<3>(gt.h[hseq&1], hseq, hsh);
    __syncthreads();
    {
      const float4* hx = reinterpret_cast<const float4*>(hsh) + l16;
      float acc = 0.f;
      #pragma unroll
      for (int i = 0; i < 12; ++i){
        float4 w = wo[16*i], x = hx[16*i];
        acc = fmaf(w.x,x.x, fmaf(w.y,x.y, fmaf(w.z,x.z, fmaf(w.w,x.w, acc))));
      }
      acc += __shfl_xor(acc,8); acc += __shfl_xor(acc,4);
      acc += __shfl_xor(acc,2); acc += __shfl_xor(acc,1);
      if (l16 == 0) kc[kslot(st+1)][ro] = acc + bo;
    }
    __syncthreads();
    // ---- local folding: next-stage z / y1 / err partial (owned 16 elements) ----
    if (st >= 1 && st <= 5){
      ++zseq;
      if (tid < 16){
        float s = 0.f;
        for (int j = 1; j <= st+1; ++j) s += d_AT[st+1][j-1] * kc[kslot(j)][tid];
        const float zv = ysl[tid] + dte * s;
        stT(&gt.z[zseq&1][gi], zseq, zv);
        if (st == 5) y1sl[tid] = zv;
      }
    }
    if (st == 6){
      ++pseq;
      if (tid < 16){
        float ev = 0.f;
        for (int j = 1; j <= 7; ++j) ev += d_EC[j-1] * kc[kslot(j)][tid];
        ev *= dte;
        const float sc = 1e-6f + 1e-3f * fmaxf(fabsf(ysl[tid]), fabsf(y1sl[tid]));
        const float q = ev / sc;
        float v = q*q;
        v += __shfl_xor(v,8); v += __shfl_xor(v,4); v += __shfl_xor(v,2); v += __shfl_xor(v,1);
        if (tid == 0) stT(&gt.p[pseq&1][blk], pseq, v);
      }
    }
  };

  // k1 = f(y0) once; FSAL-carried afterwards
  feval(0, 0.f);

  float t = 0.f, dtv = 0.1f;
  for (int iv = 1; iv < 100; ++iv){
    const float t1 = (float)iv / 99.0f;
    for (int a = 0; a < 6; ++a){
      if (t >= t1 - 1e-10f) break;
      if (tid == 0) s_ab = abort_now();
      __syncthreads();
      if (s_ab) return;                // fail fast, never wedge
      const float dte = fminf(dtv, t1 - t);

      // z for stage 2 from block-local k1 slice
      ++zseq;
      if (tid < 16)
        stT(&gt.z[zseq&1][gi], zseq, ysl[tid] + dte * 0.161f * kc[kslot(1)][tid]);

      feval(1,dte); feval(2,dte); feval(3,dte);
      feval(4,dte); feval(5,dte); feval(6,dte);

      // err: poll 192 tagged partials, deterministic fixed-order reduce
      float v = 0.f;
      if (tid < NBLK) v = pollT1(&gt.p[pseq&1][tid], pseq);
      v += __shfl_xor(v,32); v += __shfl_xor(v,16); v += __shfl_xor(v,8);
      v += __shfl_xor(v,4);  v += __shfl_xor(v,2);  v += __shfl_xor(v,1);
      if (lane == 0) red[wave] = v;
      __syncthreads();
      const float err = sqrtf((red[0]+red[1]+red[2]+red[3]) * (1.0f/3072.0f));
      __syncthreads();

      const bool accept = (err <= 1.0f);
      const float factor = fminf(fmaxf(0.9f * powf(fmaxf(err, 1e-10f), -0.2f), 0.2f), 10.0f);
      if (accept){
        t += dte;
        if (tid < 16) ysl[tid] = y1sl[tid];
        kpar ^= 1;
      }
      dtv = dte * factor;
      __syncthreads();
    }
    t = t1;
    // output emission: fully block-local thanks to permuted W_out ownership
    if (tid < 4){
      const int m = blk*4 + tid;
      out[(size_t)iv*HID + m] = ysl[tid] + eps[(size_t)iv*HID + m] * ysl[4 + tid];
    }
    __syncthreads();
  }
}

extern "C" void kernel_launch(void* const* d_in, const int* in_sizes, int n_in,
                              void* d_out, int out_size, void* d_ws, size_t ws_size,
                              hipStream_t stream) {
  const float* y0   = (const float*)d_in[0];
  const float* Win  = (const float*)d_in[1];
  const float* bin  = (const float*)d_in[2];
  const float* Whid = (const float*)d_in[3];
  const float* bhid = (const float*)d_in[4];
  const float* Wout = (const float*)d_in[5];
  const float* bout = (const float*)d_in[6];
  const float* eps  = (const float*)d_in[7];
  float* out = (float*)d_out;
  (void)in_sizes; (void)n_in; (void)out_size; (void)d_ws; (void)ws_size;

  reset_kernel<<<dim3(32), dim3(BLK), 0, stream>>>();
  ode_kernel<<<dim3(NBLK), dim3(BLK), 0, stream>>>(y0, Win, bin, Whid, bhid, Wout, bout, eps, out);
}

// Round 8
// 13119.148 us; speedup vs baseline: 1.1496x; 1.1496x over previous
//
#include <hip/hip_runtime.h>
#include <math.h>

#define NBLK 96
#define BLK  512
#define NSTATE 3072
#define HID  768
typedef unsigned long long u64;
typedef unsigned int u32;

__device__ const float d_AT[7][6] = {
  {0.f,0.f,0.f,0.f,0.f,0.f},
  {0.161f,0.f,0.f,0.f,0.f,0.f},
  {-0.008480655492356989f,0.335480655492357f,0.f,0.f,0.f,0.f},
  {2.8971530571054935f,-6.359448489975075f,4.3622954328695815f,0.f,0.f,0.f},
  {5.325864828439257f,-11.748883564062828f,7.4955393428898365f,-0.09249506636175525f,0.f,0.f},
  {5.86145544294642f,-12.92096931784711f,8.159367898576159f,-0.071584973281401f,-0.028269050394068383f,0.f},
  {0.09646076681806523f,0.01f,0.4798896504144996f,1.379008574103742f,-3.290069515436081f,2.324710524099774f},
};
__device__ const float d_EC[7] = {
  -0.001780011052226f,-0.000816434459657f,0.007880878010262f,-0.144711007173263f,
   0.582357165452555f,-0.458082105929187f,0.015151515151515152f };

// Cross-block state: {tag:hi32, value:lo32} words, ping-pong buffered.
struct GT { u64 h[2][HID]; u64 z[2][NSTATE]; u64 p[2][NBLK]; };
__device__ GT gt;
__device__ int g_abort;

__global__ void reset_kernel(){
  u64* w = reinterpret_cast<u64*>(&gt);
  const int n = (int)(sizeof(GT)/8);
  for (int i = blockIdx.x*blockDim.x + threadIdx.x; i < n; i += gridDim.x*blockDim.x)
    __hip_atomic_store(w + i, 0ull, __ATOMIC_RELAXED, __HIP_MEMORY_SCOPE_AGENT);
  if (blockIdx.x == 0 && threadIdx.x == 0)
    __hip_atomic_store(&g_abort, 0, __ATOMIC_RELAXED, __HIP_MEMORY_SCOPE_AGENT);
}

__device__ __forceinline__ int abort_now(){
  return __hip_atomic_load(&g_abort, __ATOMIC_RELAXED, __HIP_MEMORY_SCOPE_AGENT);
}
__device__ __forceinline__ void raise_abort(){
  __hip_atomic_store(&g_abort, 1, __ATOMIC_RELAXED, __HIP_MEMORY_SCOPE_AGENT);
}
__device__ __forceinline__ void stT(u64* p, u32 tag, float v){
  u32 b; __builtin_memcpy(&b, &v, 4);
  __hip_atomic_store(p, ((u64)tag << 32) | (u64)b, __ATOMIC_RELAXED, __HIP_MEMORY_SCOPE_AGENT);
}
// Single tagged-word poll; guard bail raises abort (fail fast, never wedge).
__device__ __forceinline__ float pollT1(const u64* p, u32 tag){
  u64* q = const_cast<u64*>(p);
  u64 w = __hip_atomic_load(q, __ATOMIC_RELAXED, __HIP_MEMORY_SCOPE_AGENT);
  u32 guard = 0;
  while ((u32)(w >> 32) != tag){
    if ((guard & 255u) == 255u && abort_now()) break;
    if (++guard > (1u<<18)){ raise_abort(); break; }
    __builtin_amdgcn_s_sleep(1);
    w = __hip_atomic_load(q, __ATOMIC_RELAXED, __HIP_MEMORY_SCOPE_AGENT);
  }
  u32 b = (u32)w; float v; __builtin_memcpy(&v, &b, 4); return v;
}
// Batched poll over CNT tagged words (NW per thread, stride BLK); re-polls stale only.
template<int NW, int CNT>
__device__ __forceinline__ void pollW(const u64* src, u32 tag, float* dst){
  const int tid = threadIdx.x;
  u64* s = const_cast<u64*>(src);
  u64 w[NW];
  #pragma unroll
  for (int r = 0; r < NW; ++r){
    const int i = tid + BLK*r;
    w[r] = (i < CNT) ? __hip_atomic_load(s + i, __ATOMIC_RELAXED, __HIP_MEMORY_SCOPE_AGENT)
                     : ((u64)tag << 32);
  }
  u32 guard = 0;
  for (;;){
    bool all = true;
    #pragma unroll
    for (int r = 0; r < NW; ++r) if ((u32)(w[r] >> 32) != tag) all = false;
    if (all) break;
    if ((guard & 255u) == 255u && abort_now()) break;
    if (++guard > (1u<<18)){ raise_abort(); break; }
    __builtin_amdgcn_s_sleep(1);
    #pragma unroll
    for (int r = 0; r < NW; ++r)
      if ((u32)(w[r] >> 32) != tag)
        w[r] = __hip_atomic_load(s + tid + BLK*r, __ATOMIC_RELAXED, __HIP_MEMORY_SCOPE_AGENT);
  }
  #pragma unroll
  for (int r = 0; r < NW; ++r){
    const int i = tid + BLK*r;
    if (i < CNT){ u32 b = (u32)w[r]; float v; __builtin_memcpy(&v, &b, 4); dst[i] = v; }
  }
}

__device__ __forceinline__ float softplus_f(float x){
  return fmaxf(x, 0.0f) + log1pf(expf(-fabsf(x)));
}

__global__ __launch_bounds__(BLK)
void ode_kernel(const float* __restrict__ y0p,
                const float* __restrict__ Win,  const float* __restrict__ bin,
                const float* __restrict__ Whid, const float* __restrict__ bhid,
                const float* __restrict__ Wout, const float* __restrict__ bout,
                const float* __restrict__ eps,  float* __restrict__ out)
{
  __shared__ float zsh[NSTATE];
  __shared__ float hsh[HID];
  __shared__ float kc[7][32];
  __shared__ float ysl[32], y1sl[32];
  __shared__ float red[8];
  __shared__ int s_ab;

  const int tid  = threadIdx.x, blk = blockIdx.x;
  const int wave = tid >> 6, lane = tid & 63;
  const int l16  = lane & 15;
  const int ro   = tid >> 4;                       // local out-slot 0..31
  const int row1 = blk*8 + wave;                   // layer1/hidden row (1 wave/row, 8/block)
  // Permuted W_out ownership: slot ro=(c,q), c=ro>>3, q=ro&7 -> row c*768 + blk*8 + q.
  // Block's y-slice = mean[8b..8b+8) (c=0) and std[8b..8b+8) (c=1): output emission local.
  const int orow = (ro >> 3)*HID + blk*8 + (ro & 7);

  const float4* w1  = reinterpret_cast<const float4*>(Win  + (size_t)row1*NSTATE) + lane;
  const float4* wh0 = reinterpret_cast<const float4*>(Whid + ((size_t)0*HID + row1)*HID) + lane;
  const float4* wh1 = reinterpret_cast<const float4*>(Whid + ((size_t)1*HID + row1)*HID) + lane;
  const float4* wh2 = reinterpret_cast<const float4*>(Whid + ((size_t)2*HID + row1)*HID) + lane;
  const float4* wo  = reinterpret_cast<const float4*>(Wout + (size_t)orow*HID) + l16;
  const float b1 = bin[row1];
  const float bh0 = bhid[row1], bh1 = bhid[HID+row1], bh2 = bhid[2*HID+row1];
  const float bo = bout[orow];

  // owned y/z global index for slot s (s<32): gi = (s>>3)*768 + blk*8 + (s&7)
  const int gi = (tid >> 3)*HID + blk*8 + (tid & 7);    // valid for tid<32

  if (tid < 32) ysl[tid] = y0p[gi];
  if (tid < 8){ const int e = blk*8 + tid; out[e] = y0p[e] + eps[e]*y0p[HID+e]; }
  __syncthreads();

  u32 hseq = 0, zseq = 0, pseq = 0;
  int kpar = 0;
  auto kslot = [&](int j){ return (j==1) ? (kpar?6:0) : (j==7) ? (kpar?0:6) : (j-1); };

  auto feval = [&](int st, float dte){
    // ---- acquire z ----
    if (st == 0){
      const float4* s4 = reinterpret_cast<const float4*>(y0p);
      float4* d4 = reinterpret_cast<float4*>(zsh);
      #pragma unroll
      for (int r = 0; r < 2; ++r){ const int i = tid + BLK*r; if (i < NSTATE/4) d4[i] = s4[i]; }
    } else {
      pollW<6, NSTATE>(gt.z[zseq&1], zseq, zsh);
    }
    __syncthreads();
    // ---- layer 1: 768x3072, 1 wave/row ----
    {
      const float4* zl = reinterpret_cast<const float4*>(zsh) + lane;
      float acc = 0.f;
      #pragma unroll
      for (int i = 0; i < 12; ++i){
        float4 w = w1[64*i], x = zl[64*i];
        acc = fmaf(w.x,x.x, fmaf(w.y,x.y, fmaf(w.z,x.z, fmaf(w.w,x.w, acc))));
      }
      acc += __shfl_xor(acc,32); acc += __shfl_xor(acc,16); acc += __shfl_xor(acc,8);
      acc += __shfl_xor(acc,4);  acc += __shfl_xor(acc,2);  acc += __shfl_xor(acc,1);
      ++hseq;
      if (lane == 0) stT(&gt.h[hseq&1][row1], hseq, softplus_f(acc + b1));
    }
    // ---- 3 hidden layers: 768x768 ----
    #pragma unroll
    for (int l = 0; l < 3; ++l){
      pollW<2, HID>(gt.h[hseq&1], hseq, hsh);
      __syncthreads();
      const float4* wr = (l==0) ? wh0 : (l==1) ? wh1 : wh2;
      const float bh  = (l==0) ? bh0 : (l==1) ? bh1 : bh2;
      const float4* hx = reinterpret_cast<const float4*>(hsh) + lane;
      float acc = 0.f;
      #pragma unroll
      for (int i = 0; i < 3; ++i){
        float4 w = wr[64*i], x = hx[64*i];
        acc = fmaf(w.x,x.x, fmaf(w.y,x.y, fmaf(w.z,x.z, fmaf(w.w,x.w, acc))));
      }
      acc += __shfl_xor(acc,32); acc += __shfl_xor(acc,16); acc += __shfl_xor(acc,8);
      acc += __shfl_xor(acc,4);  acc += __shfl_xor(acc,2);  acc += __shfl_xor(acc,1);
      ++hseq;
      if (lane == 0) stT(&gt.h[hseq&1][row1], hseq, softplus_f(acc + bh));
      __syncthreads();            // hsh stable until all lanes finished reading
    }
    // ---- out layer: 3072x768, 16 lanes/row, permuted ownership ----
    pollW<2, HID>(gt.h[hseq&1], hseq, hsh);
    __syncthreads();
    {
      const float4* hx = reinterpret_cast<const float4*>(hsh) + l16;
      float acc = 0.f;
      #pragma unroll
      for (int i = 0; i < 12; ++i){
        float4 w = wo[16*i], x = hx[16*i];
        acc = fmaf(w.x,x.x, fmaf(w.y,x.y, fmaf(w.z,x.z, fmaf(w.w,x.w, acc))));
      }
      acc += __shfl_xor(acc,8); acc += __shfl_xor(acc,4);
      acc += __shfl_xor(acc,2); acc += __shfl_xor(acc,1);
      if (l16 == 0) kc[kslot(st+1)][ro] = acc + bo;
    }
    __syncthreads();
    // ---- local folding: next-stage z / y1 / err partial (owned 32 elements) ----
    if (st >= 1 && st <= 5){
      ++zseq;
      if (tid < 32){
        float s = 0.f;
        for (int j = 1; j <= st+1; ++j) s += d_AT[st+1][j-1] * kc[kslot(j)][tid];
        const float zv = ysl[tid] + dte * s;
        stT(&gt.z[zseq&1][gi], zseq, zv);
        if (st == 5) y1sl[tid] = zv;
      }
    }
    if (st == 6){
      ++pseq;
      if (tid < 32){
        float ev = 0.f;
        for (int j = 1; j <= 7; ++j) ev += d_EC[j-1] * kc[kslot(j)][tid];
        ev *= dte;
        const float sc = 1e-6f + 1e-3f * fmaxf(fabsf(ysl[tid]), fabsf(y1sl[tid]));
        const float q = ev / sc;
        float v = q*q;
        v += __shfl_xor(v,16); v += __shfl_xor(v,8);
        v += __shfl_xor(v,4);  v += __shfl_xor(v,2); v += __shfl_xor(v,1);
        if (tid == 0) stT(&gt.p[pseq&1][blk], pseq, v);
      }
    }
  };

  // k1 = f(y0) once; FSAL-carried afterwards
  feval(0, 0.f);

  float t = 0.f, dtv = 0.1f;
  for (int iv = 1; iv < 100; ++iv){
    const float t1 = (float)iv / 99.0f;
    for (int a = 0; a < 6; ++a){
      if (t >= t1 - 1e-10f) break;
      if (tid == 0) s_ab = abort_now();
      __syncthreads();
      if (s_ab) return;                // fail fast, never wedge
      const float dte = fminf(dtv, t1 - t);

      // z for stage 2 from block-local k1 slice
      ++zseq;
      if (tid < 32)
        stT(&gt.z[zseq&1][gi], zseq, ysl[tid] + dte * 0.161f * kc[kslot(1)][tid]);

      feval(1,dte); feval(2,dte); feval(3,dte);
      feval(4,dte); feval(5,dte); feval(6,dte);

      // err: poll 96 tagged partials, deterministic fixed-order reduce
      float v = 0.f;
      if (tid < NBLK) v = pollT1(&gt.p[pseq&1][tid], pseq);
      v += __shfl_xor(v,32); v += __shfl_xor(v,16); v += __shfl_xor(v,8);
      v += __shfl_xor(v,4);  v += __shfl_xor(v,2);  v += __shfl_xor(v,1);
      if (lane == 0) red[wave] = v;
      __syncthreads();
      const float err = sqrtf((red[0]+red[1]) * (1.0f/3072.0f));
      __syncthreads();

      const bool accept = (err <= 1.0f);
      const float factor = fminf(fmaxf(0.9f * powf(fmaxf(err, 1e-10f), -0.2f), 0.2f), 10.0f);
      if (accept){
        t += dte;
        if (tid < 32) ysl[tid] = y1sl[tid];
        kpar ^= 1;
      }
      dtv = dte * factor;
      __syncthreads();
    }
    t = t1;
    // output emission: fully block-local thanks to permuted W_out ownership
    if (tid < 8){
      const int m = blk*8 + tid;
      out[(size_t)iv*HID + m] = ysl[tid] + eps[(size_t)iv*HID + m] * ysl[8 + tid];
    }
    __syncthreads();
  }
}

extern "C" void kernel_launch(void* const* d_in, const int* in_sizes, int n_in,
                              void* d_out, int out_size, void* d_ws, size_t ws_size,
                              hipStream_t stream) {
  const float* y0   = (const float*)d_in[0];
  const float* Win  = (const float*)d_in[1];
  const float* bin  = (const float*)d_in[2];
  const float* Whid = (const float*)d_in[3];
  const float* bhid = (const float*)d_in[4];
  const float* Wout = (const float*)d_in[5];
  const float* bout = (const float*)d_in[6];
  const float* eps  = (const float*)d_in[7];
  float* out = (float*)d_out;
  (void)in_sizes; (void)n_in; (void)out_size; (void)d_ws; (void)ws_size;

  reset_kernel<<<dim3(16), dim3(BLK), 0, stream>>>();
  ode_kernel<<<dim3(NBLK), dim3(BLK), 0, stream>>>(y0, Win, bin, Whid, bhid, Wout, bout, eps, out);
}

// Round 9
// 9398.529 us; speedup vs baseline: 1.6048x; 1.3959x over previous
//
#include <hip/hip_runtime.h>
#include <math.h>

#define NBLK 96
#define BLK  512
#define NSTATE 3072
#define HID  768
typedef unsigned long long u64;
typedef unsigned int u32;

__device__ const float d_AT[7][6] = {
  {0.f,0.f,0.f,0.f,0.f,0.f},
  {0.161f,0.f,0.f,0.f,0.f,0.f},
  {-0.008480655492356989f,0.335480655492357f,0.f,0.f,0.f,0.f},
  {2.8971530571054935f,-6.359448489975075f,4.3622954328695815f,0.f,0.f,0.f},
  {5.325864828439257f,-11.748883564062828f,7.4955393428898365f,-0.09249506636175525f,0.f,0.f},
  {5.86145544294642f,-12.92096931784711f,8.159367898576159f,-0.071584973281401f,-0.028269050394068383f,0.f},
  {0.09646076681806523f,0.01f,0.4798896504144996f,1.379008574103742f,-3.290069515436081f,2.324710524099774f},
};
__device__ const float d_EC[7] = {
  -0.001780011052226f,-0.000816434459657f,0.007880878010262f,-0.144711007173263f,
   0.582357165452555f,-0.458082105929187f,0.015151515151515152f };

namespace {
constexpr float SBc = 0.09646076681806523f+0.01f+0.4798896504144996f
                    +1.379008574103742f+(-3.290069515436081f)+2.324710524099774f;
constexpr float SEc = -0.001780011052226f-0.000816434459657f+0.007880878010262f
                      -0.144711007173263f+0.582357165452555f-0.458082105929187f
                      +0.015151515151515152f;
}

// Cross-block state: {tag:hi32, value:lo32} words, ping-pong buffered.
struct GT { u64 h[2][HID]; u64 p[2][NBLK]; };
__device__ GT gt;
__device__ int g_abort;
// Precomputed M = W_in @ W_out (768x768) and c0 = W_in @ b_out (768)
__device__ __align__(16) float g_M[HID*HID];
__device__ float g_c0[HID];

__global__ void reset_kernel(){
  u64* w = reinterpret_cast<u64*>(&gt);
  const int n = (int)(sizeof(GT)/8);
  for (int i = blockIdx.x*blockDim.x + threadIdx.x; i < n; i += gridDim.x*blockDim.x)
    __hip_atomic_store(w + i, 0ull, __ATOMIC_RELAXED, __HIP_MEMORY_SCOPE_AGENT);
  if (blockIdx.x == 0 && threadIdx.x == 0)
    __hip_atomic_store(&g_abort, 0, __ATOMIC_RELAXED, __HIP_MEMORY_SCOPE_AGENT);
}

// M[r,c] = sum_i Win[r,i]*Wout[i,c];  c0[r] = sum_i Win[r,i]*bout[i]
__global__ __launch_bounds__(BLK)
void prep_kernel(const float* __restrict__ Win, const float* __restrict__ Wout,
                 const float* __restrict__ bout){
  const int blk = blockIdx.x;            // 96 blocks, 8 rows each
  const int t = threadIdx.x;
  const int rl = t >> 6, lane = t & 63;
  const int r = blk*8 + rl;
  // c0 via wave-parallel dot
  {
    const float4* wr = reinterpret_cast<const float4*>(Win + (size_t)r*NSTATE) + lane;
    const float4* bo = reinterpret_cast<const float4*>(bout) + lane;
    float acc = 0.f;
    #pragma unroll
    for (int i = 0; i < 12; ++i){
      float4 w = wr[64*i], b = bo[64*i];
      acc = fmaf(w.x,b.x, fmaf(w.y,b.y, fmaf(w.z,b.z, fmaf(w.w,b.w, acc))));
    }
    acc += __shfl_xor(acc,32); acc += __shfl_xor(acc,16); acc += __shfl_xor(acc,8);
    acc += __shfl_xor(acc,4);  acc += __shfl_xor(acc,2);  acc += __shfl_xor(acc,1);
    if (lane == 0) g_c0[r] = acc;
  }
  // M rows: thread owns 12 consecutive columns cb..cb+11
  const int cb = (t & 63) * 12;
  float acc[12];
  #pragma unroll
  for (int m = 0; m < 12; ++m) acc[m] = 0.f;
  const float* wrow = Win + (size_t)r*NSTATE;
  for (int i = 0; i < NSTATE; ++i){
    const float wv = wrow[i];
    const float4* wo = reinterpret_cast<const float4*>(Wout + (size_t)i*HID + cb);
    float4 a0 = wo[0], a1 = wo[1], a2 = wo[2];
    acc[0]=fmaf(wv,a0.x,acc[0]); acc[1]=fmaf(wv,a0.y,acc[1]);
    acc[2]=fmaf(wv,a0.z,acc[2]); acc[3]=fmaf(wv,a0.w,acc[3]);
    acc[4]=fmaf(wv,a1.x,acc[4]); acc[5]=fmaf(wv,a1.y,acc[5]);
    acc[6]=fmaf(wv,a1.z,acc[6]); acc[7]=fmaf(wv,a1.w,acc[7]);
    acc[8]=fmaf(wv,a2.x,acc[8]); acc[9]=fmaf(wv,a2.y,acc[9]);
    acc[10]=fmaf(wv,a2.z,acc[10]); acc[11]=fmaf(wv,a2.w,acc[11]);
  }
  #pragma unroll
  for (int m = 0; m < 12; ++m) g_M[(size_t)r*HID + cb + m] = acc[m];
}

__device__ __forceinline__ int abort_now(){
  return __hip_atomic_load(&g_abort, __ATOMIC_RELAXED, __HIP_MEMORY_SCOPE_AGENT);
}
__device__ __forceinline__ void raise_abort(){
  __hip_atomic_store(&g_abort, 1, __ATOMIC_RELAXED, __HIP_MEMORY_SCOPE_AGENT);
}
__device__ __forceinline__ void stT(u64* p, u32 tag, float v){
  u32 b; __builtin_memcpy(&b, &v, 4);
  __hip_atomic_store(p, ((u64)tag << 32) | (u64)b, __ATOMIC_RELAXED, __HIP_MEMORY_SCOPE_AGENT);
}
__device__ __forceinline__ float pollT1(const u64* p, u32 tag){
  u64* q = const_cast<u64*>(p);
  u64 w = __hip_atomic_load(q, __ATOMIC_RELAXED, __HIP_MEMORY_SCOPE_AGENT);
  u32 guard = 0;
  while ((u32)(w >> 32) != tag){
    if ((guard & 255u) == 255u && abort_now()) break;
    if (++guard > (1u<<18)){ raise_abort(); break; }
    __builtin_amdgcn_s_sleep(1);
    w = __hip_atomic_load(q, __ATOMIC_RELAXED, __HIP_MEMORY_SCOPE_AGENT);
  }
  u32 b = (u32)w; float v; __builtin_memcpy(&v, &b, 4); return v;
}
// Batched poll over CNT tagged words (NW per thread, stride BLK); re-polls stale only.
template<int NW, int CNT>
__device__ __forceinline__ void pollW(const u64* src, u32 tag, float* dst){
  const int tid = threadIdx.x;
  u64* s = const_cast<u64*>(src);
  u64 w[NW];
  #pragma unroll
  for (int r = 0; r < NW; ++r){
    const int i = tid + BLK*r;
    w[r] = (i < CNT) ? __hip_atomic_load(s + i, __ATOMIC_RELAXED, __HIP_MEMORY_SCOPE_AGENT)
                     : ((u64)tag << 32);
  }
  u32 guard = 0;
  for (;;){
    bool all = true;
    #pragma unroll
    for (int r = 0; r < NW; ++r) if ((u32)(w[r] >> 32) != tag) all = false;
    if (all) break;
    if ((guard & 255u) == 255u && abort_now()) break;
    if (++guard > (1u<<18)){ raise_abort(); break; }
    __builtin_amdgcn_s_sleep(1);
    #pragma unroll
    for (int r = 0; r < NW; ++r){
      const int i = tid + BLK*r;
      if (i < CNT && (u32)(w[r] >> 32) != tag)
        w[r] = __hip_atomic_load(s + i, __ATOMIC_RELAXED, __HIP_MEMORY_SCOPE_AGENT);
    }
  }
  #pragma unroll
  for (int r = 0; r < NW; ++r){
    const int i = tid + BLK*r;
    if (i < CNT){ u32 b = (u32)w[r]; float v; __builtin_memcpy(&v, &b, 4); dst[i] = v; }
  }
}

__device__ __forceinline__ float softplus_f(float x){
  return fmaxf(x, 0.0f) + log1pf(expf(-fabsf(x)));
}

__global__ __launch_bounds__(BLK)
void ode_kernel(const float* __restrict__ y0p,
                const float* __restrict__ Win,  const float* __restrict__ bin,
                const float* __restrict__ Whid, const float* __restrict__ bhid,
                const float* __restrict__ Wout, const float* __restrict__ bout,
                const float* __restrict__ eps,  float* __restrict__ out)
{
  __shared__ float h4s[8][HID];      // retained h4 per k-slot (1..7); [0..3] doubles as y0 scratch
  __shared__ float hsh[HID];         // h gather buffer
  __shared__ float hBs[HID], hEs[HID];
  __shared__ float us[8][8];         // u_j[local row], slot-indexed
  __shared__ float vsl[8], b1s[8];
  __shared__ float ysl[32], y1sl[32], esl[32];
  __shared__ float red[8];
  __shared__ int s_ab;

  const int tid  = threadIdx.x, blk = blockIdx.x;
  const int wave = tid >> 6, lane = tid & 63;
  const int l16  = lane & 15;
  const int ro   = tid >> 4;                   // out-slot 0..31
  const int row1 = blk*8 + wave;               // h-row (hidden/M/h1), 1 wave per row
  // Permuted W_out ownership: slot (c,q) -> row c*768 + blk*8 + q  => output block-local
  const int orow = (ro >> 3)*HID + blk*8 + (ro & 7);
  const int gi   = (tid >> 3)*HID + blk*8 + (tid & 7);   // owned y index (tid<32)

  const float4* wh0 = reinterpret_cast<const float4*>(Whid + ((size_t)0*HID + row1)*HID) + lane;
  const float4* wh1 = reinterpret_cast<const float4*>(Whid + ((size_t)1*HID + row1)*HID) + lane;
  const float4* wh2 = reinterpret_cast<const float4*>(Whid + ((size_t)2*HID + row1)*HID) + lane;
  const float4* mr  = reinterpret_cast<const float4*>(g_M  + (size_t)row1*HID) + lane;
  const float4* wo  = reinterpret_cast<const float4*>(Wout + (size_t)orow*HID) + l16;
  const float bh0 = bhid[row1], bh1 = bhid[HID+row1], bh2 = bhid[2*HID+row1];
  const float c0r = g_c0[row1];
  const float bo_r = bout[orow];

  // ---- init: ysl, b1s, v = Win·y0 (local, via y0 staged in LDS scratch) ----
  if (tid < 32) ysl[tid] = y0p[gi];
  if (lane == 0) b1s[wave] = bin[row1];
  if (tid < 8){ const int e = blk*8 + tid; out[e] = y0p[e] + eps[e]*y0p[HID+e]; }
  {
    float* scratch = &h4s[0][0];               // 3072 floats
    float4* d4 = reinterpret_cast<float4*>(scratch);
    const float4* s4 = reinterpret_cast<const float4*>(y0p);
    #pragma unroll
    for (int r = 0; r < 2; ++r){ const int i = tid + BLK*r; if (i < NSTATE/4) d4[i] = s4[i]; }
    __syncthreads();
    const float4* wr = reinterpret_cast<const float4*>(Win + (size_t)row1*NSTATE) + lane;
    const float4* zl = reinterpret_cast<const float4*>(scratch) + lane;
    float acc = 0.f;
    #pragma unroll
    for (int i = 0; i < 12; ++i){
      float4 w = wr[64*i], x = zl[64*i];
      acc = fmaf(w.x,x.x, fmaf(w.y,x.y, fmaf(w.z,x.z, fmaf(w.w,x.w, acc))));
    }
    acc += __shfl_xor(acc,32); acc += __shfl_xor(acc,16); acc += __shfl_xor(acc,8);
    acc += __shfl_xor(acc,4);  acc += __shfl_xor(acc,2);  acc += __shfl_xor(acc,1);
    if (lane == 0) vsl[wave] = acc;            // v = Win·y (no bias)
    __syncthreads();
  }

  u32 hseq = 0, pseq = 0;
  int kpar = 0;
  auto slot = [&](int j){ return (j==1) ? (kpar?7:1) : (j==7) ? (kpar?1:7) : j; };

  // one f-eval in u-space: h1 from scalars -> 3 hidden hops -> h4 hop -> M-matvec
  auto stage = [&](int s, float dte){
    __syncthreads();
    const int tg = slot(s + 1);
    // h1 rows are owner-local scalars
    ++hseq;
    if (tid < 8){
      float a = 0.f;
      for (int j = 1; j <= s; ++j) a += d_AT[s][j-1] * us[slot(j)][tid];
      stT(&gt.h[hseq&1][blk*8 + tid], hseq, softplus_f(vsl[tid] + dte*a + b1s[tid]));
    }
    pollW<2, HID>(gt.h[hseq&1], hseq, hsh);
    __syncthreads();
    #pragma unroll
    for (int l = 0; l < 3; ++l){
      const float4* wr = (l==0) ? wh0 : (l==1) ? wh1 : wh2;
      const float bh  = (l==0) ? bh0 : (l==1) ? bh1 : bh2;
      const float4* hx = reinterpret_cast<const float4*>(hsh) + lane;
      float acc = 0.f;
      #pragma unroll
      for (int i = 0; i < 3; ++i){
        float4 w = wr[64*i], x = hx[64*i];
        acc = fmaf(w.x,x.x, fmaf(w.y,x.y, fmaf(w.z,x.z, fmaf(w.w,x.w, acc))));
      }
      acc += __shfl_xor(acc,32); acc += __shfl_xor(acc,16); acc += __shfl_xor(acc,8);
      acc += __shfl_xor(acc,4);  acc += __shfl_xor(acc,2);  acc += __shfl_xor(acc,1);
      ++hseq;
      if (lane == 0) stT(&gt.h[hseq&1][row1], hseq, softplus_f(acc + bh));
      pollW<2, HID>(gt.h[hseq&1], hseq, (l < 2) ? hsh : h4s[tg]);
      __syncthreads();
    }
    // u_{s+1} = M·h4 + c0  (owner-local)
    {
      const float4* hx = reinterpret_cast<const float4*>(h4s[tg]) + lane;
      float acc = 0.f;
      #pragma unroll
      for (int i = 0; i < 3; ++i){
        float4 w = mr[64*i], x = hx[64*i];
        acc = fmaf(w.x,x.x, fmaf(w.y,x.y, fmaf(w.z,x.z, fmaf(w.w,x.w, acc))));
      }
      acc += __shfl_xor(acc,32); acc += __shfl_xor(acc,16); acc += __shfl_xor(acc,8);
      acc += __shfl_xor(acc,4);  acc += __shfl_xor(acc,2);  acc += __shfl_xor(acc,1);
      if (lane == 0) us[tg][wave] = acc + c0r;
    }
  };

  // k1 = f(y0) once; FSAL-carried afterwards
  stage(0, 0.f);

  float t = 0.f, dtv = 0.1f;
  for (int iv = 1; iv < 100; ++iv){
    const float t1 = (float)iv / 99.0f;
    for (int a = 0; a < 6; ++a){
      if (t >= t1 - 1e-10f) break;
      if (tid == 0) s_ab = abort_now();
      __syncthreads();
      if (s_ab) return;                        // fail fast, never wedge
      const float dte = fminf(dtv, t1 - t);

      stage(1,dte); stage(2,dte); stage(3,dte);
      stage(4,dte); stage(5,dte); stage(6,dte);
      __syncthreads();

      // hB = Σ B_j h4_j ; hE = Σ E_j h4_j (elementwise, local)
      for (int c = tid; c < HID; c += BLK){
        float hb = 0.f, he = 0.f;
        for (int j = 1; j <= 6; ++j) hb = fmaf(d_AT[6][j-1], h4s[slot(j)][c], hb);
        for (int j = 1; j <= 7; ++j) he = fmaf(d_EC[j-1],    h4s[slot(j)][c], he);
        hBs[c] = hb; hEs[c] = he;
      }
      __syncthreads();
      // y1, e on owned out-rows: two dots against Wout row
      {
        const float4* hb4 = reinterpret_cast<const float4*>(hBs) + l16;
        const float4* he4 = reinterpret_cast<const float4*>(hEs) + l16;
        float ab = 0.f, ae = 0.f;
        #pragma unroll
        for (int i = 0; i < 12; ++i){
          float4 w = wo[16*i], xb = hb4[16*i], xe = he4[16*i];
          ab = fmaf(w.x,xb.x, fmaf(w.y,xb.y, fmaf(w.z,xb.z, fmaf(w.w,xb.w, ab))));
          ae = fmaf(w.x,xe.x, fmaf(w.y,xe.y, fmaf(w.z,xe.z, fmaf(w.w,xe.w, ae))));
        }
        ab += __shfl_xor(ab,8); ab += __shfl_xor(ab,4); ab += __shfl_xor(ab,2); ab += __shfl_xor(ab,1);
        ae += __shfl_xor(ae,8); ae += __shfl_xor(ae,4); ae += __shfl_xor(ae,2); ae += __shfl_xor(ae,1);
        if (l16 == 0){
          y1sl[ro] = ysl[ro] + dte*(ab + SBc*bo_r);
          esl[ro]  = dte*(ae + SEc*bo_r);
        }
      }
      __syncthreads();
      // err partial over owned 32 elements -> publish
      ++pseq;
      if (tid < 32){
        const float sc = 1e-6f + 1e-3f * fmaxf(fabsf(ysl[tid]), fabsf(y1sl[tid]));
        const float q = esl[tid] / sc;
        float v = q*q;
        v += __shfl_xor(v,16); v += __shfl_xor(v,8);
        v += __shfl_xor(v,4);  v += __shfl_xor(v,2); v += __shfl_xor(v,1);
        if (tid == 0) stT(&gt.p[pseq&1][blk], pseq, v);
      }
      // gather 96 partials, deterministic fixed-order reduce
      float v = 0.f;
      if (tid < NBLK) v = pollT1(&gt.p[pseq&1][tid], pseq);
      v += __shfl_xor(v,32); v += __shfl_xor(v,16); v += __shfl_xor(v,8);
      v += __shfl_xor(v,4);  v += __shfl_xor(v,2);  v += __shfl_xor(v,1);
      if (lane == 0) red[wave] = v;
      __syncthreads();
      const float err = sqrtf((red[0]+red[1]) * (1.0f/3072.0f));
      __syncthreads();

      const bool accept = (err <= 1.0f);
      const float factor = fminf(fmaxf(0.9f * powf(fmaxf(err, 1e-10f), -0.2f), 0.2f), 10.0f);
      if (accept){
        t += dte;
        if (tid < 32) ysl[tid] = y1sl[tid];
        if (tid < 8){
          float s = 0.f;
          for (int j = 1; j <= 6; ++j) s += d_AT[6][j-1] * us[slot(j)][tid];
          vsl[tid] += dte * s;                 // v = Win·y1 exactly (u-algebra)
        }
        kpar ^= 1;                             // k1 <- k7 (u & h4 slot swap)
      }
      dtv = dte * factor;
      __syncthreads();
    }
    t = t1;
    // output emission: block-local thanks to permuted W_out ownership
    if (tid < 8){
      const int m = blk*8 + tid;
      out[(size_t)iv*HID + m] = ysl[tid] + eps[(size_t)iv*HID + m] * ysl[8 + tid];
    }
    __syncthreads();
  }
}

extern "C" void kernel_launch(void* const* d_in, const int* in_sizes, int n_in,
                              void* d_out, int out_size, void* d_ws, size_t ws_size,
                              hipStream_t stream) {
  const float* y0   = (const float*)d_in[0];
  const float* Win  = (const float*)d_in[1];
  const float* bin  = (const float*)d_in[2];
  const float* Whid = (const float*)d_in[3];
  const float* bhid = (const float*)d_in[4];
  const float* Wout = (const float*)d_in[5];
  const float* bout = (const float*)d_in[6];
  const float* eps  = (const float*)d_in[7];
  float* out = (float*)d_out;
  (void)in_sizes; (void)n_in; (void)out_size; (void)d_ws; (void)ws_size;

  reset_kernel<<<dim3(4), dim3(BLK), 0, stream>>>();
  prep_kernel<<<dim3(NBLK), dim3(BLK), 0, stream>>>(Win, Wout, bout);
  ode_kernel<<<dim3(NBLK), dim3(BLK), 0, stream>>>(y0, Win, bin, Whid, bhid, Wout, bout, eps, out);
}

// Round 11
// 7838.851 us; speedup vs baseline: 1.9241x; 1.1990x over previous
//
#include <hip/hip_runtime.h>
#include <math.h>

#define NBLK 96
#define BLK  512
#define NSTATE 3072
#define HID  768
typedef unsigned long long u64;
typedef unsigned int u32;

__device__ const float d_AT[7][6] = {
  {0.f,0.f,0.f,0.f,0.f,0.f},
  {0.161f,0.f,0.f,0.f,0.f,0.f},
  {-0.008480655492356989f,0.335480655492357f,0.f,0.f,0.f,0.f},
  {2.8971530571054935f,-6.359448489975075f,4.3622954328695815f,0.f,0.f,0.f},
  {5.325864828439257f,-11.748883564062828f,7.4955393428898365f,-0.09249506636175525f,0.f,0.f},
  {5.86145544294642f,-12.92096931784711f,8.159367898576159f,-0.071584973281401f,-0.028269050394068383f,0.f},
  {0.09646076681806523f,0.01f,0.4798896504144996f,1.379008574103742f,-3.290069515436081f,2.324710524099774f},
};
__device__ const float d_EC[7] = {
  -0.001780011052226f,-0.000816434459657f,0.007880878010262f,-0.144711007173263f,
   0.582357165452555f,-0.458082105929187f,0.015151515151515152f };

namespace {
constexpr float SBc = 0.09646076681806523f+0.01f+0.4798896504144996f
                    +1.379008574103742f+(-3.290069515436081f)+2.324710524099774f;
constexpr float SEc = -0.001780011052226f-0.000816434459657f+0.007880878010262f
                      -0.144711007173263f+0.582357165452555f-0.458082105929187f
                      +0.015151515151515152f;
}

// Cross-block state: {tag:hi32, value:lo32} words, ping-pong buffered.
struct GT { u64 h[2][HID]; u64 p[2][NBLK]; };
__device__ GT gt;
__device__ int g_abort;
// Precomputed M = W_in @ W_out (768x768) and c0 = W_in @ b_out (768)
__device__ __align__(16) float g_M[HID*HID];
__device__ float g_c0[HID];

__global__ void reset_kernel(){
  u64* w = reinterpret_cast<u64*>(&gt);
  const int n = (int)(sizeof(GT)/8);
  for (int i = blockIdx.x*blockDim.x + threadIdx.x; i < n; i += gridDim.x*blockDim.x)
    __hip_atomic_store(w + i, 0ull, __ATOMIC_RELAXED, __HIP_MEMORY_SCOPE_AGENT);
  if (blockIdx.x == 0 && threadIdx.x == 0)
    __hip_atomic_store(&g_abort, 0, __ATOMIC_RELAXED, __HIP_MEMORY_SCOPE_AGENT);
}

// M[r,c] = sum_i Win[r,i]*Wout[i,c];  c0[r] = sum_i Win[r,i]*bout[i]
__global__ __launch_bounds__(512)
void prep_kernel(const float* __restrict__ Win, const float* __restrict__ Wout,
                 const float* __restrict__ bout){
  const int blk = blockIdx.x;
  const int t = threadIdx.x;
  const int rl = t >> 6, lane = t & 63;
  const int r = blk*8 + rl;
  {
    const float4* wr = reinterpret_cast<const float4*>(Win + (size_t)r*NSTATE) + lane;
    const float4* bo = reinterpret_cast<const float4*>(bout) + lane;
    float acc = 0.f;
    #pragma unroll
    for (int i = 0; i < 12; ++i){
      float4 w = wr[64*i], b = bo[64*i];
      acc = fmaf(w.x,b.x, fmaf(w.y,b.y, fmaf(w.z,b.z, fmaf(w.w,b.w, acc))));
    }
    acc += __shfl_xor(acc,32); acc += __shfl_xor(acc,16); acc += __shfl_xor(acc,8);
    acc += __shfl_xor(acc,4);  acc += __shfl_xor(acc,2);  acc += __shfl_xor(acc,1);
    if (lane == 0) g_c0[r] = acc;
  }
  const int cb = (t & 63) * 12;
  float acc[12];
  #pragma unroll
  for (int m = 0; m < 12; ++m) acc[m] = 0.f;
  const float* wrow = Win + (size_t)r*NSTATE;
  for (int i = 0; i < NSTATE; ++i){
    const float wv = wrow[i];
    const float4* wo = reinterpret_cast<const float4*>(Wout + (size_t)i*HID + cb);
    float4 a0 = wo[0], a1 = wo[1], a2 = wo[2];
    acc[0]=fmaf(wv,a0.x,acc[0]); acc[1]=fmaf(wv,a0.y,acc[1]);
    acc[2]=fmaf(wv,a0.z,acc[2]); acc[3]=fmaf(wv,a0.w,acc[3]);
    acc[4]=fmaf(wv,a1.x,acc[4]); acc[5]=fmaf(wv,a1.y,acc[5]);
    acc[6]=fmaf(wv,a1.z,acc[6]); acc[7]=fmaf(wv,a1.w,acc[7]);
    acc[8]=fmaf(wv,a2.x,acc[8]); acc[9]=fmaf(wv,a2.y,acc[9]);
    acc[10]=fmaf(wv,a2.z,acc[10]); acc[11]=fmaf(wv,a2.w,acc[11]);
  }
  #pragma unroll
  for (int m = 0; m < 12; ++m) g_M[(size_t)r*HID + cb + m] = acc[m];
}

__device__ __forceinline__ int abort_now(){
  return __hip_atomic_load(&g_abort, __ATOMIC_RELAXED, __HIP_MEMORY_SCOPE_AGENT);
}
__device__ __forceinline__ void raise_abort(){
  __hip_atomic_store(&g_abort, 1, __ATOMIC_RELAXED, __HIP_MEMORY_SCOPE_AGENT);
}
__device__ __forceinline__ void stT(u64* p, u32 tag, float v){
  u32 b; __builtin_memcpy(&b, &v, 4);
  __hip_atomic_store(p, ((u64)tag << 32) | (u64)b, __ATOMIC_RELAXED, __HIP_MEMORY_SCOPE_AGENT);
}
__device__ __forceinline__ float pollT1(const u64* p, u32 tag){
  u64* q = const_cast<u64*>(p);
  u64 w = __hip_atomic_load(q, __ATOMIC_RELAXED, __HIP_MEMORY_SCOPE_AGENT);
  u32 guard = 0;
  while ((u32)(w >> 32) != tag){
    if ((guard & 63u) == 63u && abort_now()) break;
    if (++guard > (1u<<16)){ raise_abort(); break; }
    __builtin_amdgcn_s_sleep(1);
    w = __hip_atomic_load(q, __ATOMIC_RELAXED, __HIP_MEMORY_SCOPE_AGENT);
  }
  u32 b = (u32)w; float v; __builtin_memcpy(&v, &b, 4); return v;
}
// Batched poll over CNT tagged words (NW per thread, stride BLK); re-polls stale only.
template<int NW, int CNT>
__device__ __forceinline__ void pollW(const u64* src, u32 tag, float* dst){
  const int tid = threadIdx.x;
  u64* s = const_cast<u64*>(src);
  u64 w[NW];
  #pragma unroll
  for (int r = 0; r < NW; ++r){
    const int i = tid + BLK*r;
    w[r] = (i < CNT) ? __hip_atomic_load(s + i, __ATOMIC_RELAXED, __HIP_MEMORY_SCOPE_AGENT)
                     : ((u64)tag << 32);
  }
  u32 guard = 0;
  for (;;){
    bool all = true;
    #pragma unroll
    for (int r = 0; r < NW; ++r) if ((u32)(w[r] >> 32) != tag) all = false;
    if (all) break;
    if ((guard & 63u) == 63u && abort_now()) break;
    if (++guard > (1u<<16)){ raise_abort(); break; }
    __builtin_amdgcn_s_sleep(1);
    #pragma unroll
    for (int r = 0; r < NW; ++r){
      const int i = tid + BLK*r;
      if (i < CNT && (u32)(w[r] >> 32) != tag)
        w[r] = __hip_atomic_load(s + i, __ATOMIC_RELAXED, __HIP_MEMORY_SCOPE_AGENT);
    }
  }
  #pragma unroll
  for (int r = 0; r < NW; ++r){
    const int i = tid + BLK*r;
    if (i < CNT){ u32 b = (u32)w[r]; float v; __builtin_memcpy(&v, &b, 4); dst[i] = v; }
  }
}

__device__ __forceinline__ float softplus_f(float x){
  return fmaxf(x, 0.0f) + log1pf(expf(-fabsf(x)));
}

__global__ __launch_bounds__(BLK)
void ode_kernel(const float* __restrict__ y0p,
                const float* __restrict__ Win,  const float* __restrict__ bin,
                const float* __restrict__ Whid, const float* __restrict__ bhid,
                const float* __restrict__ Wout, const float* __restrict__ bout,
                const float* __restrict__ eps,  float* __restrict__ out)
{
  __shared__ float h4s[8][HID];      // retained h4 per slot (1..7); [0..3] = y0 scratch at init
  __shared__ float hsh[HID];
  __shared__ float hBs[HID], hEs[HID];
  __shared__ float us[8][8];
  __shared__ float vsl[8], b1s[8];
  __shared__ float ysl[32], y1sl[32], esl[32];
  __shared__ float red[8];
  __shared__ int s_ab;

  const int tid  = threadIdx.x, blk = blockIdx.x;
  const int wave = tid >> 6, lane = tid & 63;
  const int l16  = lane & 15;
  const int ro   = tid >> 4;                   // out-slot 0..31
  const int row1 = blk*8 + wave;               // h-row (hidden/M/h1), 1 wave per row
  const int orow = (ro >> 3)*HID + blk*8 + (ro & 7);
  const int gi   = (tid >> 3)*HID + blk*8 + (tid & 7);   // owned y index (tid<32)

  // ---- preload hidden + M weight rows into registers (loop-invariant) ----
  float4 wr0[3], wr1[3], wr2[3], mreg[3];
  {
    const float4* b0 = reinterpret_cast<const float4*>(Whid + ((size_t)0*HID + row1)*HID) + lane;
    const float4* b1 = reinterpret_cast<const float4*>(Whid + ((size_t)1*HID + row1)*HID) + lane;
    const float4* b2 = reinterpret_cast<const float4*>(Whid + ((size_t)2*HID + row1)*HID) + lane;
    const float4* mb = reinterpret_cast<const float4*>(g_M  + (size_t)row1*HID) + lane;
    #pragma unroll
    for (int i = 0; i < 3; ++i){
      wr0[i] = b0[64*i]; wr1[i] = b1[64*i]; wr2[i] = b2[64*i]; mreg[i] = mb[64*i];
    }
  }
  const float4* wo  = reinterpret_cast<const float4*>(Wout + (size_t)orow*HID) + l16;
  const float bh0 = bhid[row1], bh1 = bhid[HID+row1], bh2 = bhid[2*HID+row1];
  const float c0r = g_c0[row1];
  const float bo_r = bout[orow];

  // ---- init: ysl, b1s, v = Win·y0 (local, via y0 staged in LDS scratch) ----
  if (tid < 32) ysl[tid] = y0p[gi];
  if (lane == 0) b1s[wave] = bin[row1];
  if (tid < 8){ const int e = blk*8 + tid; out[e] = y0p[e] + eps[e]*y0p[HID+e]; }
  {
    float* scratch = &h4s[0][0];               // 3072 floats
    float4* d4 = reinterpret_cast<float4*>(scratch);
    const float4* s4 = reinterpret_cast<const float4*>(y0p);
    #pragma unroll
    for (int r = 0; r < 2; ++r){ const int i = tid + BLK*r; if (i < NSTATE/4) d4[i] = s4[i]; }
    __syncthreads();
    const float4* wr = reinterpret_cast<const float4*>(Win + (size_t)row1*NSTATE) + lane;
    const float4* zl = reinterpret_cast<const float4*>(scratch) + lane;
    float acc = 0.f;
    #pragma unroll
    for (int i = 0; i < 12; ++i){
      float4 w = wr[64*i], x = zl[64*i];
      acc = fmaf(w.x,x.x, fmaf(w.y,x.y, fmaf(w.z,x.z, fmaf(w.w,x.w, acc))));
    }
    acc += __shfl_xor(acc,32); acc += __shfl_xor(acc,16); acc += __shfl_xor(acc,8);
    acc += __shfl_xor(acc,4);  acc += __shfl_xor(acc,2);  acc += __shfl_xor(acc,1);
    if (lane == 0) vsl[wave] = acc;            // v = Win·y (no bias)
    __syncthreads();
  }

  u32 hseq = 0, pseq = 0;
  int kpar = 0;
  auto slot = [&](int j){ return (j==1) ? (kpar?7:1) : (j==7) ? (kpar?1:7) : j; };

  // one f-eval in u-space: h1 from scalars -> 3 hidden hops -> h4 hop -> M-matvec
  auto stage = [&](int s, float dte){
    __syncthreads();
    const int tg = slot(s + 1);
    ++hseq;
    if (tid < 8){
      float a = 0.f;
      for (int j = 1; j <= s; ++j) a += d_AT[s][j-1] * us[slot(j)][tid];
      stT(&gt.h[hseq&1][blk*8 + tid], hseq, softplus_f(vsl[tid] + dte*a + b1s[tid]));
    }
    pollW<2, HID>(gt.h[hseq&1], hseq, hsh);
    __syncthreads();
    #pragma unroll
    for (int l = 0; l < 3; ++l){
      const float4* hx = reinterpret_cast<const float4*>(hsh) + lane;
      float acc = 0.f;
      #pragma unroll
      for (int i = 0; i < 3; ++i){
        float4 w = (l==0) ? wr0[i] : (l==1) ? wr1[i] : wr2[i];
        float4 x = hx[64*i];
        acc = fmaf(w.x,x.x, fmaf(w.y,x.y, fmaf(w.z,x.z, fmaf(w.w,x.w, acc))));
      }
      acc += __shfl_xor(acc,32); acc += __shfl_xor(acc,16); acc += __shfl_xor(acc,8);
      acc += __shfl_xor(acc,4);  acc += __shfl_xor(acc,2);  acc += __shfl_xor(acc,1);
      const float bh = (l==0) ? bh0 : (l==1) ? bh1 : bh2;
      ++hseq;
      if (lane == 0) stT(&gt.h[hseq&1][row1], hseq, softplus_f(acc + bh));
      __syncthreads();           // RACE FIX: all hsh reads done before pollW overwrites it
      pollW<2, HID>(gt.h[hseq&1], hseq, (l < 2) ? hsh : h4s[tg]);
      __syncthreads();
    }
    // u_{s+1} = M·h4 + c0 (owner-local, M in registers)
    {
      const float4* hx = reinterpret_cast<const float4*>(h4s[tg]) + lane;
      float acc = 0.f;
      #pragma unroll
      for (int i = 0; i < 3; ++i){
        float4 w = mreg[i], x = hx[64*i];
        acc = fmaf(w.x,x.x, fmaf(w.y,x.y, fmaf(w.z,x.z, fmaf(w.w,x.w, acc))));
      }
      acc += __shfl_xor(acc,32); acc += __shfl_xor(acc,16); acc += __shfl_xor(acc,8);
      acc += __shfl_xor(acc,4);  acc += __shfl_xor(acc,2);  acc += __shfl_xor(acc,1);
      if (lane == 0) us[tg][wave] = acc + c0r;
    }
  };

  // k1 = f(y0) once; FSAL-carried afterwards
  stage(0, 0.f);

  float t = 0.f, dtv = 0.1f;
  for (int iv = 1; iv < 100; ++iv){
    const float t1 = (float)iv / 99.0f;
    for (int a = 0; a < 6; ++a){
      if (t >= t1 - 1e-10f) break;
      if (tid == 0) s_ab = abort_now();
      __syncthreads();
      if (s_ab) return;                        // fail fast, never wedge
      const float dte = fminf(dtv, t1 - t);

      stage(1,dte); stage(2,dte); stage(3,dte);
      stage(4,dte); stage(5,dte); stage(6,dte);
      __syncthreads();

      // hB = Σ B_j h4_j ; hE = Σ E_j h4_j (elementwise, local)
      for (int c = tid; c < HID; c += BLK){
        float hb = 0.f, he = 0.f;
        for (int j = 1; j <= 6; ++j) hb = fmaf(d_AT[6][j-1], h4s[slot(j)][c], hb);
        for (int j = 1; j <= 7; ++j) he = fmaf(d_EC[j-1],    h4s[slot(j)][c], he);
        hBs[c] = hb; hEs[c] = he;
      }
      __syncthreads();
      // y1, e on owned out-rows: two dots against Wout row
      {
        const float4* hb4 = reinterpret_cast<const float4*>(hBs) + l16;
        const float4* he4 = reinterpret_cast<const float4*>(hEs) + l16;
        float ab = 0.f, ae = 0.f;
        #pragma unroll
        for (int i = 0; i < 12; ++i){
          float4 w = wo[16*i], xb = hb4[16*i], xe = he4[16*i];
          ab = fmaf(w.x,xb.x, fmaf(w.y,xb.y, fmaf(w.z,xb.z, fmaf(w.w,xb.w, ab))));
          ae = fmaf(w.x,xe.x, fmaf(w.y,xe.y, fmaf(w.z,xe.z, fmaf(w.w,xe.w, ae))));
        }
        ab += __shfl_xor(ab,8); ab += __shfl_xor(ab,4); ab += __shfl_xor(ab,2); ab += __shfl_xor(ab,1);
        ae += __shfl_xor(ae,8); ae += __shfl_xor(ae,4); ae += __shfl_xor(ae,2); ae += __shfl_xor(ae,1);
        if (l16 == 0){
          y1sl[ro] = ysl[ro] + dte*(ab + SBc*bo_r);
          esl[ro]  = dte*(ae + SEc*bo_r);
        }
      }
      __syncthreads();
      // err partial over owned 32 elements -> publish
      ++pseq;
      if (tid < 32){
        const float sc = 1e-6f + 1e-3f * fmaxf(fabsf(ysl[tid]), fabsf(y1sl[tid]));
        const float q = esl[tid] / sc;
        float v = q*q;
        v += __shfl_xor(v,16); v += __shfl_xor(v,8);
        v += __shfl_xor(v,4);  v += __shfl_xor(v,2); v += __shfl_xor(v,1);
        if (tid == 0) stT(&gt.p[pseq&1][blk], pseq, v);
      }
      // gather 96 partials, deterministic fixed-order reduce
      float v = 0.f;
      if (tid < NBLK) v = pollT1(&gt.p[pseq&1][tid], pseq);
      v += __shfl_xor(v,32); v += __shfl_xor(v,16); v += __shfl_xor(v,8);
      v += __shfl_xor(v,4);  v += __shfl_xor(v,2);  v += __shfl_xor(v,1);
      if (lane == 0) red[wave] = v;
      __syncthreads();
      const float err = sqrtf((red[0]+red[1]) * (1.0f/3072.0f));
      __syncthreads();

      const bool accept = (err <= 1.0f);
      const float factor = fminf(fmaxf(0.9f * powf(fmaxf(err, 1e-10f), -0.2f), 0.2f), 10.0f);
      if (accept){
        t += dte;
        if (tid < 32) ysl[tid] = y1sl[tid];
        if (tid < 8){
          float s = 0.f;
          for (int j = 1; j <= 6; ++j) s += d_AT[6][j-1] * us[slot(j)][tid];
          vsl[tid] += dte * s;                 // v = Win·y1 exactly (u-algebra)
        }
        kpar ^= 1;                             // k1 <- k7 (u & h4 slot swap)
      }
      dtv = dte * factor;
      __syncthreads();
    }
    t = t1;
    // output emission: block-local thanks to permuted W_out ownership
    if (tid < 8){
      const int m = blk*8 + tid;
      out[(size_t)iv*HID + m] = ysl[tid] + eps[(size_t)iv*HID + m] * ysl[8 + tid];
    }
    __syncthreads();
  }
}

extern "C" void kernel_launch(void* const* d_in, const int* in_sizes, int n_in,
                              void* d_out, int out_size, void* d_ws, size_t ws_size,
                              hipStream_t stream) {
  const float* y0   = (const float*)d_in[0];
  const float* Win  = (const float*)d_in[1];
  const float* bin  = (const float*)d_in[2];
  const float* Whid = (const float*)d_in[3];
  const float* bhid = (const float*)d_in[4];
  const float* Wout = (const float*)d_in[5];
  const float* bout = (const float*)d_in[6];
  const float* eps  = (const float*)d_in[7];
  float* out = (float*)d_out;
  (void)in_sizes; (void)n_in; (void)out_size; (void)d_ws; (void)ws_size;

  reset_kernel<<<dim3(4), dim3(BLK), 0, stream>>>();
  prep_kernel<<<dim3(96), dim3(512), 0, stream>>>(Win, Wout, bout);
  ode_kernel<<<dim3(NBLK), dim3(BLK), 0, stream>>>(y0, Win, bin, Whid, bhid, Wout, bout, eps, out);
}

// Round 12
// 6932.226 us; speedup vs baseline: 2.1757x; 1.1308x over previous
//
#include <hip/hip_runtime.h>
#include <math.h>

#define NBLK 48
#define BLK  512
#define NSTATE 3072
#define HID  768
typedef unsigned long long u64;
typedef unsigned int u32;

__device__ const float d_AT[7][6] = {
  {0.f,0.f,0.f,0.f,0.f,0.f},
  {0.161f,0.f,0.f,0.f,0.f,0.f},
  {-0.008480655492356989f,0.335480655492357f,0.f,0.f,0.f,0.f},
  {2.8971530571054935f,-6.359448489975075f,4.3622954328695815f,0.f,0.f,0.f},
  {5.325864828439257f,-11.748883564062828f,7.4955393428898365f,-0.09249506636175525f,0.f,0.f},
  {5.86145544294642f,-12.92096931784711f,8.159367898576159f,-0.071584973281401f,-0.028269050394068383f,0.f},
  {0.09646076681806523f,0.01f,0.4798896504144996f,1.379008574103742f,-3.290069515436081f,2.324710524099774f},
};
__device__ const float d_EC[7] = {
  -0.001780011052226f,-0.000816434459657f,0.007880878010262f,-0.144711007173263f,
   0.582357165452555f,-0.458082105929187f,0.015151515151515152f };

namespace {
constexpr float SBc = 0.09646076681806523f+0.01f+0.4798896504144996f
                    +1.379008574103742f+(-3.290069515436081f)+2.324710524099774f;
constexpr float SEc = -0.001780011052226f-0.000816434459657f+0.007880878010262f
                      -0.144711007173263f+0.582357165452555f-0.458082105929187f
                      +0.015151515151515152f;
}

// Cross-block state: {tag:hi32, value:lo32} words, ping-pong buffered.
struct GT { u64 h[2][HID]; u64 p[2][NBLK]; };
__device__ GT gt;
__device__ int g_abort;
// Precomputed M = W_in @ W_out (768x768) and c0 = W_in @ b_out (768)
__device__ __align__(16) float g_M[HID*HID];
__device__ float g_c0[HID];

__global__ void reset_kernel(){
  u64* w = reinterpret_cast<u64*>(&gt);
  const int n = (int)(sizeof(GT)/8);
  for (int i = blockIdx.x*blockDim.x + threadIdx.x; i < n; i += gridDim.x*blockDim.x)
    __hip_atomic_store(w + i, 0ull, __ATOMIC_RELAXED, __HIP_MEMORY_SCOPE_AGENT);
  if (blockIdx.x == 0 && threadIdx.x == 0)
    __hip_atomic_store(&g_abort, 0, __ATOMIC_RELAXED, __HIP_MEMORY_SCOPE_AGENT);
}

// prep: 96 blocks x 8 rows. Win rows staged in 96KB dynamic LDS (broadcast reads);
// Wout read exactly ONCE per block (coalesced); 8 k-segments reduced via LDS.
__global__ __launch_bounds__(512, 1)
void prep_kernel(const float* __restrict__ Win, const float* __restrict__ Wout,
                 const float* __restrict__ bout){
  extern __shared__ float wl[];                 // 8*3072 floats; head reused as reduce buf
  const int blk = blockIdx.x;
  const int t = threadIdx.x;
  {
    const float4* wsrc = reinterpret_cast<const float4*>(Win + (size_t)blk*8*NSTATE);
    float4* wdst = reinterpret_cast<float4*>(wl);
    for (int i = t; i < 8*NSTATE/4; i += 512) wdst[i] = wsrc[i];
  }
  __syncthreads();
  const int seg = t >> 6;                       // wave index = k-segment (broadcast-friendly)
  const int cb  = (t & 63) * 12;
  float acc[8][12];
  #pragma unroll
  for (int r = 0; r < 8; ++r)
    #pragma unroll
    for (int j = 0; j < 12; ++j) acc[r][j] = 0.f;
  const int k0 = seg * 384;
  for (int k = 0; k < 384; ++k){
    const float4* wo4 = reinterpret_cast<const float4*>(Wout + (size_t)(k0 + k)*HID + cb);
    const float4 a0 = wo4[0], a1 = wo4[1], a2 = wo4[2];
    #pragma unroll
    for (int r = 0; r < 8; ++r){
      const float wv = wl[r*NSTATE + k0 + k];   // same addr across wave -> LDS broadcast
      acc[r][0]=fmaf(wv,a0.x,acc[r][0]); acc[r][1]=fmaf(wv,a0.y,acc[r][1]);
      acc[r][2]=fmaf(wv,a0.z,acc[r][2]); acc[r][3]=fmaf(wv,a0.w,acc[r][3]);
      acc[r][4]=fmaf(wv,a1.x,acc[r][4]); acc[r][5]=fmaf(wv,a1.y,acc[r][5]);
      acc[r][6]=fmaf(wv,a1.z,acc[r][6]); acc[r][7]=fmaf(wv,a1.w,acc[r][7]);
      acc[r][8]=fmaf(wv,a2.x,acc[r][8]); acc[r][9]=fmaf(wv,a2.y,acc[r][9]);
      acc[r][10]=fmaf(wv,a2.z,acc[r][10]); acc[r][11]=fmaf(wv,a2.w,acc[r][11]);
    }
  }
  __syncthreads();                              // Win staging no longer needed
  for (int r = 0; r < 8; ++r){
    #pragma unroll
    for (int j = 0; j < 12; ++j) wl[seg*HID + cb + j] = acc[r][j];
    __syncthreads();
    for (int c = t; c < HID; c += 512){
      float s2 = 0.f;
      #pragma unroll
      for (int s3 = 0; s3 < 8; ++s3) s2 += wl[s3*HID + c];
      g_M[(size_t)(blk*8 + r)*HID + c] = s2;
    }
    __syncthreads();
  }
  // c0 rows (Win L2-hot now)
  {
    const int rl = t >> 6, lane = t & 63;
    const int r = blk*8 + rl;
    const float4* wr = reinterpret_cast<const float4*>(Win + (size_t)r*NSTATE) + lane;
    const float4* bo = reinterpret_cast<const float4*>(bout) + lane;
    float a2c = 0.f;
    #pragma unroll
    for (int i = 0; i < 12; ++i){
      float4 w = wr[64*i], b = bo[64*i];
      a2c = fmaf(w.x,b.x, fmaf(w.y,b.y, fmaf(w.z,b.z, fmaf(w.w,b.w, a2c))));
    }
    a2c += __shfl_xor(a2c,32); a2c += __shfl_xor(a2c,16); a2c += __shfl_xor(a2c,8);
    a2c += __shfl_xor(a2c,4);  a2c += __shfl_xor(a2c,2);  a2c += __shfl_xor(a2c,1);
    if (lane == 0) g_c0[r] = a2c;
  }
}

__device__ __forceinline__ int abort_now(){
  return __hip_atomic_load(&g_abort, __ATOMIC_RELAXED, __HIP_MEMORY_SCOPE_AGENT);
}
__device__ __forceinline__ void raise_abort(){
  __hip_atomic_store(&g_abort, 1, __ATOMIC_RELAXED, __HIP_MEMORY_SCOPE_AGENT);
}
__device__ __forceinline__ void stT(u64* p, u32 tag, float v){
  u32 b; __builtin_memcpy(&b, &v, 4);
  __hip_atomic_store(p, ((u64)tag << 32) | (u64)b, __ATOMIC_RELAXED, __HIP_MEMORY_SCOPE_AGENT);
}
__device__ __forceinline__ float pollT1(const u64* p, u32 tag){
  u64* q = const_cast<u64*>(p);
  u64 w = __hip_atomic_load(q, __ATOMIC_RELAXED, __HIP_MEMORY_SCOPE_AGENT);
  u32 guard = 0;
  while ((u32)(w >> 32) != tag){
    if ((guard & 63u) == 63u && abort_now()) break;
    if (++guard > (1u<<16)){ raise_abort(); break; }
    __builtin_amdgcn_s_sleep(1);
    w = __hip_atomic_load(q, __ATOMIC_RELAXED, __HIP_MEMORY_SCOPE_AGENT);
  }
  u32 b = (u32)w; float v; __builtin_memcpy(&v, &b, 4); return v;
}
template<int NW, int CNT>
__device__ __forceinline__ void pollW(const u64* src, u32 tag, float* dst){
  const int tid = threadIdx.x;
  u64* s = const_cast<u64*>(src);
  u64 w[NW];
  #pragma unroll
  for (int r = 0; r < NW; ++r){
    const int i = tid + BLK*r;
    w[r] = (i < CNT) ? __hip_atomic_load(s + i, __ATOMIC_RELAXED, __HIP_MEMORY_SCOPE_AGENT)
                     : ((u64)tag << 32);
  }
  u32 guard = 0;
  for (;;){
    bool all = true;
    #pragma unroll
    for (int r = 0; r < NW; ++r) if ((u32)(w[r] >> 32) != tag) all = false;
    if (all) break;
    if ((guard & 63u) == 63u && abort_now()) break;
    if (++guard > (1u<<16)){ raise_abort(); break; }
    __builtin_amdgcn_s_sleep(1);
    #pragma unroll
    for (int r = 0; r < NW; ++r){
      const int i = tid + BLK*r;
      if (i < CNT && (u32)(w[r] >> 32) != tag)
        w[r] = __hip_atomic_load(s + i, __ATOMIC_RELAXED, __HIP_MEMORY_SCOPE_AGENT);
    }
  }
  #pragma unroll
  for (int r = 0; r < NW; ++r){
    const int i = tid + BLK*r;
    if (i < CNT){ u32 b = (u32)w[r]; float v; __builtin_memcpy(&v, &b, 4); dst[i] = v; }
  }
}

__device__ __forceinline__ float softplus_f(float x){
  return fmaxf(x, 0.0f) + log1pf(expf(-fabsf(x)));
}

__global__ __launch_bounds__(BLK)
void ode_kernel(const float* __restrict__ y0p,
                const float* __restrict__ Win,  const float* __restrict__ bin,
                const float* __restrict__ Whid, const float* __restrict__ bhid,
                const float* __restrict__ Wout, const float* __restrict__ bout,
                const float* __restrict__ eps,  float* __restrict__ out)
{
  __shared__ float h4s[8][HID];      // retained h4 per slot (1..7); [0..3] = y0 scratch at init
  __shared__ float hshA[HID], hshB[HID];
  __shared__ float hBs[HID], hEs[HID];
  __shared__ float us[8][16];
  __shared__ float vsl[16], b1s[16];
  __shared__ float ysl[64], y1sl[64], esl[64];
  __shared__ float red0;
  __shared__ int s_ab;

  const int tid  = threadIdx.x, blk = blockIdx.x;
  const int wave = tid >> 6, lane = tid & 63;
  const int hl = lane >> 5, lane32 = lane & 31;
  const int hrow = blk*16 + wave*2 + hl;            // hidden/M row (2 per wave, 16 per block)
  const int ro = tid >> 3, l8 = tid & 7;            // out-slot 0..63, 8 lanes/row
  const int orow = (ro >> 4)*HID + blk*16 + (ro & 15);
  const int gi   = (tid >> 4)*HID + blk*16 + (tid & 15);   // owned y index (tid<64)

  // ---- preload hidden + M weight rows into registers (loop-invariant) ----
  float4 wr0[6], wr1[6], wr2[6], mreg[6];
  {
    const float4* b0 = reinterpret_cast<const float4*>(Whid + ((size_t)0*HID + hrow)*HID) + lane32;
    const float4* b1 = reinterpret_cast<const float4*>(Whid + ((size_t)1*HID + hrow)*HID) + lane32;
    const float4* b2 = reinterpret_cast<const float4*>(Whid + ((size_t)2*HID + hrow)*HID) + lane32;
    const float4* mb = reinterpret_cast<const float4*>(g_M  + (size_t)hrow*HID) + lane32;
    #pragma unroll
    for (int i = 0; i < 6; ++i){
      wr0[i] = b0[32*i]; wr1[i] = b1[32*i]; wr2[i] = b2[32*i]; mreg[i] = mb[32*i];
    }
  }
  const float4* wo4 = reinterpret_cast<const float4*>(Wout + (size_t)orow*HID) + l8;
  const float bh0 = bhid[hrow], bh1v = bhid[HID+hrow], bh2v = bhid[2*HID+hrow];
  const float c0r = g_c0[hrow];
  const float bo_r = bout[orow];

  // ---- init ----
  if (tid < 64) ysl[tid] = y0p[gi];
  if (tid < 16) b1s[tid] = bin[blk*16 + tid];
  if (tid < 16){ const int e = blk*16 + tid; out[e] = y0p[e] + eps[e]*y0p[HID+e]; }
  {
    float* scratch = &h4s[0][0];
    float4* d4 = reinterpret_cast<float4*>(scratch);
    const float4* s4 = reinterpret_cast<const float4*>(y0p);
    #pragma unroll
    for (int r = 0; r < 2; ++r){ const int i = tid + BLK*r; if (i < NSTATE/4) d4[i] = s4[i]; }
    __syncthreads();
    const int vrow = blk*16 + (tid >> 5);
    const int v32 = tid & 31;
    const float4* wr = reinterpret_cast<const float4*>(Win + (size_t)vrow*NSTATE) + v32;
    const float4* zl = reinterpret_cast<const float4*>(scratch) + v32;
    float acc = 0.f;
    #pragma unroll
    for (int i = 0; i < 24; ++i){
      float4 w = wr[32*i], x = zl[32*i];
      acc = fmaf(w.x,x.x, fmaf(w.y,x.y, fmaf(w.z,x.z, fmaf(w.w,x.w, acc))));
    }
    acc += __shfl_xor(acc,16); acc += __shfl_xor(acc,8);
    acc += __shfl_xor(acc,4);  acc += __shfl_xor(acc,2);  acc += __shfl_xor(acc,1);
    if (v32 == 0) vsl[tid >> 5] = acc;           // v = Win·y (no bias)
    __syncthreads();
  }

  u32 hseq = 0, pseq = 0;
  int kpar = 0;
  auto slot = [&](int j){ return (j==1) ? (kpar?7:1) : (j==7) ? (kpar?1:7) : j; };

  auto stage = [&](int s, float dte){
    __syncthreads();
    const int tg = slot(s + 1);
    ++hseq;
    if (tid < 16){
      float a = 0.f;
      for (int j = 1; j <= s; ++j) a += d_AT[s][j-1] * us[slot(j)][tid];
      stT(&gt.h[hseq&1][blk*16 + tid], hseq, softplus_f(vsl[tid] + dte*a + b1s[tid]));
    }
    pollW<2, HID>(gt.h[hseq&1], hseq, hshA);
    __syncthreads();
    #pragma unroll
    for (int l = 0; l < 3; ++l){
      const float* rbuf = (l == 1) ? hshB : hshA;         // A, B, A
      const float4* hx = reinterpret_cast<const float4*>(rbuf) + lane32;
      float acc = 0.f;
      #pragma unroll
      for (int i = 0; i < 6; ++i){
        float4 w = (l==0) ? wr0[i] : (l==1) ? wr1[i] : wr2[i];
        float4 x = hx[32*i];
        acc = fmaf(w.x,x.x, fmaf(w.y,x.y, fmaf(w.z,x.z, fmaf(w.w,x.w, acc))));
      }
      acc += __shfl_xor(acc,16); acc += __shfl_xor(acc,8);
      acc += __shfl_xor(acc,4);  acc += __shfl_xor(acc,2);  acc += __shfl_xor(acc,1);
      const float bh = (l==0) ? bh0 : (l==1) ? bh1v : bh2v;
      ++hseq;
      if (lane32 == 0) stT(&gt.h[hseq&1][hrow], hseq, softplus_f(acc + bh));
      // double-buffer: poll writes the buffer nobody is reading (no pre-sync needed)
      pollW<2, HID>(gt.h[hseq&1], hseq, (l==0) ? hshB : (l==1) ? hshA : h4s[tg]);
      __syncthreads();
    }
    // u_{s+1} = M·h4 + c0 (owner-local, M in registers)
    {
      const float4* hx = reinterpret_cast<const float4*>(h4s[tg]) + lane32;
      float acc = 0.f;
      #pragma unroll
      for (int i = 0; i < 6; ++i){
        float4 w = mreg[i], x = hx[32*i];
        acc = fmaf(w.x,x.x, fmaf(w.y,x.y, fmaf(w.z,x.z, fmaf(w.w,x.w, acc))));
      }
      acc += __shfl_xor(acc,16); acc += __shfl_xor(acc,8);
      acc += __shfl_xor(acc,4);  acc += __shfl_xor(acc,2);  acc += __shfl_xor(acc,1);
      if (lane32 == 0) us[tg][wave*2 + hl] = acc + c0r;
    }
  };

  // k1 = f(y0) once; FSAL-carried afterwards
  stage(0, 0.f);

  float t = 0.f, dtv = 0.1f;
  for (int iv = 1; iv < 100; ++iv){
    const float t1 = (float)iv / 99.0f;
    for (int a = 0; a < 6; ++a){
      if (t >= t1 - 1e-10f) break;
      if (tid == 0) s_ab = abort_now();
      __syncthreads();
      if (s_ab) return;                        // fail fast, never wedge
      const float dte = fminf(dtv, t1 - t);

      stage(1,dte); stage(2,dte); stage(3,dte);
      stage(4,dte); stage(5,dte); stage(6,dte);
      __syncthreads();

      // hB = Σ B_j h4_j ; hE = Σ E_j h4_j (elementwise, local)
      for (int c = tid; c < HID; c += BLK){
        float hb = 0.f, he = 0.f;
        for (int j = 1; j <= 6; ++j) hb = fmaf(d_AT[6][j-1], h4s[slot(j)][c], hb);
        for (int j = 1; j <= 7; ++j) he = fmaf(d_EC[j-1],    h4s[slot(j)][c], he);
        hBs[c] = hb; hEs[c] = he;
      }
      __syncthreads();
      // y1, e on owned out-rows (8 lanes/row)
      {
        const float4* hb4 = reinterpret_cast<const float4*>(hBs) + l8;
        const float4* he4 = reinterpret_cast<const float4*>(hEs) + l8;
        float ab = 0.f, ae = 0.f;
        #pragma unroll
        for (int i = 0; i < 24; ++i){
          float4 w = wo4[8*i], xb = hb4[8*i], xe = he4[8*i];
          ab = fmaf(w.x,xb.x, fmaf(w.y,xb.y, fmaf(w.z,xb.z, fmaf(w.w,xb.w, ab))));
          ae = fmaf(w.x,xe.x, fmaf(w.y,xe.y, fmaf(w.z,xe.z, fmaf(w.w,xe.w, ae))));
        }
        ab += __shfl_xor(ab,4); ab += __shfl_xor(ab,2); ab += __shfl_xor(ab,1);
        ae += __shfl_xor(ae,4); ae += __shfl_xor(ae,2); ae += __shfl_xor(ae,1);
        if (l8 == 0){
          y1sl[ro] = ysl[ro] + dte*(ab + SBc*bo_r);
          esl[ro]  = dte*(ae + SEc*bo_r);
        }
      }
      __syncthreads();
      // err partial over owned 64 elements (wave 0) -> publish
      ++pseq;
      if (tid < 64){
        const float sc = 1e-6f + 1e-3f * fmaxf(fabsf(ysl[tid]), fabsf(y1sl[tid]));
        const float q = esl[tid] / sc;
        float v = q*q;
        v += __shfl_xor(v,32); v += __shfl_xor(v,16); v += __shfl_xor(v,8);
        v += __shfl_xor(v,4);  v += __shfl_xor(v,2);  v += __shfl_xor(v,1);
        if (tid == 0) stT(&gt.p[pseq&1][blk], pseq, v);
      }
      // gather 48 partials (wave 0), deterministic fixed-order reduce
      {
        float v = 0.f;
        if (tid < NBLK) v = pollT1(&gt.p[pseq&1][tid], pseq);
        if (wave == 0){
          v += __shfl_xor(v,32); v += __shfl_xor(v,16); v += __shfl_xor(v,8);
          v += __shfl_xor(v,4);  v += __shfl_xor(v,2);  v += __shfl_xor(v,1);
          if (tid == 0) red0 = v;
        }
      }
      __syncthreads();
      const float err = sqrtf(red0 * (1.0f/3072.0f));
      __syncthreads();

      const bool accept = (err <= 1.0f);
      const float factor = fminf(fmaxf(0.9f * powf(fmaxf(err, 1e-10f), -0.2f), 0.2f), 10.0f);
      if (accept){
        t += dte;
        if (tid < 64) ysl[tid] = y1sl[tid];
        if (tid < 16){
          float s = 0.f;
          for (int j = 1; j <= 6; ++j) s += d_AT[6][j-1] * us[slot(j)][tid];
          vsl[tid] += dte * s;                 // v = Win·y1 exactly (u-algebra)
        }
        kpar ^= 1;                             // k1 <- k7 (u & h4 slot swap)
      }
      dtv = dte * factor;
      __syncthreads();
    }
    t = t1;
    // output emission: block-local thanks to permuted W_out ownership
    if (tid < 16){
      const int m = blk*16 + tid;
      out[(size_t)iv*HID + m] = ysl[tid] + eps[(size_t)iv*HID + m] * ysl[16 + tid];
    }
    __syncthreads();
  }
}

extern "C" void kernel_launch(void* const* d_in, const int* in_sizes, int n_in,
                              void* d_out, int out_size, void* d_ws, size_t ws_size,
                              hipStream_t stream) {
  const float* y0   = (const float*)d_in[0];
  const float* Win  = (const float*)d_in[1];
  const float* bin  = (const float*)d_in[2];
  const float* Whid = (const float*)d_in[3];
  const float* bhid = (const float*)d_in[4];
  const float* Wout = (const float*)d_in[5];
  const float* bout = (const float*)d_in[6];
  const float* eps  = (const float*)d_in[7];
  float* out = (float*)d_out;
  (void)in_sizes; (void)n_in; (void)out_size; (void)d_ws; (void)ws_size;

  const int prep_lds = 8 * NSTATE * 4;   // 96 KB
  (void)hipFuncSetAttribute(reinterpret_cast<const void*>(&prep_kernel),
                            hipFuncAttributeMaxDynamicSharedMemorySize, prep_lds);
  reset_kernel<<<dim3(4), dim3(BLK), 0, stream>>>();
  prep_kernel<<<dim3(96), dim3(512), prep_lds, stream>>>(Win, Wout, bout);
  ode_kernel<<<dim3(NBLK), dim3(BLK), 0, stream>>>(y0, Win, bin, Whid, bhid, Wout, bout, eps, out);
}